// Round 8
// baseline (329.855 us; speedup 1.0000x reference)
//
#include <hip/hip_runtime.h>
#include <cfloat>

#define C_DIM 256
#define HW    4096
#define NE    1024
#define NPIX  65536
#define TAU   0.15f
#define ZSTR  264   // fp16 per Z-LDS pixel row: 256 ch + 8 pad (528 B, 16B-aligned)

typedef __attribute__((ext_vector_type(8))) _Float16 half8_t;
typedef __attribute__((ext_vector_type(4))) float floatx4;

// monotone float -> uint32 (for packed (d,idx) u64 min with lowest-index tie-break)
__device__ __forceinline__ unsigned int fenc(float f) {
  unsigned int u = __float_as_uint(f);
  return (u & 0x80000000u) ? ~u : (u | 0x80000000u);
}

// ---------------- ws layout ----------------
// @0       float acc (Σ d1 + Σ z², loss numerator)  [zeroed by prep]
// @8       int   ccount                             [zeroed by prep]
// @4096    float e2[1024]
// @8192    _Float16 EhfP[1024*256]     (512 KiB fp16 codebook, MFMA-fragment-packed)
// @532480  int   clist[65536]          (256 KiB, ends 794624)

// K0 (fused): blocks [0,128) pack codebook into MFMA A-fragment order;
// blocks [128,384) compute ||e||^2 per codeword (one wave per codeword).
// Block 128 additionally zeroes acc/ccount.
__global__ __launch_bounds__(256)
void prep_kernel(const float* __restrict__ cb, _Float16* __restrict__ EhfP,
                 float* __restrict__ e2, float* __restrict__ acc,
                 int* __restrict__ ccount) {
  if (blockIdx.x < 128) {
    const int g = blockIdx.x >> 3, it = blockIdx.x & 7;
    const int sidx = it * 256 + (int)threadIdx.x;       // (ks*256 + i*64 + lane)
    const int ks = sidx >> 8, i = (sidx >> 6) & 3, lane = sidx & 63;
    const int ln = lane & 15, quad = lane >> 4;
    const float* src = cb + (size_t)(g * 64 + i * 16 + ln) * C_DIM + ks * 32 + quad * 8;
    const float4 v0 = *(const float4*)(src);
    const float4 v1 = *(const float4*)(src + 4);
    half8_t h;
    h[0] = (_Float16)v0.x; h[1] = (_Float16)v0.y; h[2] = (_Float16)v0.z; h[3] = (_Float16)v0.w;
    h[4] = (_Float16)v1.x; h[5] = (_Float16)v1.y; h[6] = (_Float16)v1.z; h[7] = (_Float16)v1.w;
    *(half8_t*)(EhfP + (size_t)g * 16384 + (size_t)sidx * 8) = h;
  } else {
    if (blockIdx.x == 128 && threadIdx.x == 0) { acc[0] = 0.f; ccount[0] = 0; }
    const int bid = blockIdx.x - 128;
    const int wave = (bid * 256 + (int)threadIdx.x) >> 6;
    const int lane = threadIdx.x & 63;
    const float4 v = *(const float4*)(cb + (size_t)wave * C_DIM + lane * 4);
    float s = v.x * v.x + v.y * v.y + v.z * v.z + v.w * v.w;
    #pragma unroll
    for (int off = 32; off; off >>= 1) s += __shfl_down(s, off, 64);
    if (lane == 0) e2[wave] = s;
  }
}

// K1: fp16 MFMA screen, 256-px tile / 8-wave block. Wave = 64 cw x 128 px
// (4x8 MFMA grid, j=8): doubles px-per-wave A-reuse vs j=4 (R4 proved j=2
// regressed; this is the inverse lever). Per ks-step: 32 MFMA (160cy busy)
// per 4 A-loads -> 2x latency tolerance at same 2 waves/SIMD. A-traffic
// halves (256 blocks x 512KB). B single-buffered (LDS ~120cy, hidden by
// setprio + wave overlap) to keep VGPR ~240 <= 256. 4 chunks x 256 cw.
__global__ __launch_bounds__(512, 2)
void screen_kernel(const float* __restrict__ z, const _Float16* __restrict__ EhfP,
                   const float* __restrict__ e2, const float* __restrict__ cb,
                   int* __restrict__ clist, int* __restrict__ ccount,
                   float* __restrict__ acc_out, float* __restrict__ out) {
  __shared__ __align__(16) _Float16 Zl[256 * ZSTR];   // 135168 B
  __shared__ float e2l[NE];                           // 4096 B

  const int tid = threadIdx.x;
  const int ptile = blockIdx.x * 256;
  const int b = ptile >> 12, pb = ptile & 4095;
  const float* zb = z + (size_t)b * (C_DIM * HW) + pb;

  // stage Z: z[k][p] fp32 -> Zl[p][k] fp16; accumulate Σz² in fp32 on the side.
  float s_z2 = 0.f;
  #pragma unroll
  for (int it = 0; it < 16; ++it) {
    const int flat = it * 512 + tid;
    const int p = flat & 255, kb = flat >> 8;
    float f[8];
    #pragma unroll
    for (int j = 0; j < 8; ++j) f[j] = zb[(size_t)(kb * 8 + j) * HW + p];
    half8_t h;
    #pragma unroll
    for (int j = 0; j < 8; ++j) { s_z2 = fmaf(f[j], f[j], s_z2); h[j] = (_Float16)f[j]; }
    *(half8_t*)&Zl[p * ZSTR + kb * 8] = h;
  }
  #pragma unroll
  for (int i = 0; i < 2; ++i) e2l[i * 512 + tid] = e2[i * 512 + tid];
  __syncthreads();

  const int lane = tid & 63;
  const int w = tid >> 6;          // 8 waves
  const int wc = w & 3, wp = w >> 2;
  const int ln = lane & 15, quad = lane >> 4;

  // A stream: chunk nc covers cw [nc*256, nc*256+256); wave wc owns its 64-cw
  // slice = fragment group (nc*4 + wc). Step s = nc*8+ks (0..31), frag i:
  // EhfP + ((s>>3)*4 + wc)*16384 + (s&7)*2048 + i*512 + lane*8 halves.
  const _Float16* aBase = EhfP + (size_t)wc * 16384 + (size_t)lane * 8;
  const char* rowB[8];
  #pragma unroll
  for (int j = 0; j < 8; ++j)
    rowB[j] = (const char*)(&Zl[(wp * 128 + j * 16 + ln) * ZSTR + quad * 8]);

  float d1[8], d2[8]; int i1[8];
  #pragma unroll
  for (int j = 0; j < 8; ++j) { d1[j] = FLT_MAX; d2[j] = FLT_MAX; i1[j] = 0; }

  half8_t abuf[2][4], bbuf[8];
  // prologue: A fragments for step 0
  #pragma unroll
  for (int i = 0; i < 4; ++i) abuf[0][i] = *(const half8_t*)(aBase + i * 512);

  for (int nc = 0; nc < 4; ++nc) {
    floatx4 acc[4][8];
    #pragma unroll
    for (int i = 0; i < 4; ++i)
      #pragma unroll
      for (int j = 0; j < 8; ++j) acc[i][j] = (floatx4){0.f, 0.f, 0.f, 0.f};

    #pragma unroll
    for (int ks = 0; ks < 8; ++ks) {
      const int s = nc * 8 + ks;
      const int cur = s & 1, nxt = cur ^ 1;
      // B for THIS step (single-buffered, LDS)
      #pragma unroll
      for (int j = 0; j < 8; ++j) bbuf[j] = *(const half8_t*)(rowB[j] + ks * 64);
      // A prefetch for step s+1 (clamped to last step: redundant reload, in-bounds)
      const int sp = s + 1 > 31 ? 31 : s + 1;
      const size_t aoff = (size_t)(sp >> 3) * 65536 + (size_t)(sp & 7) * 2048;
      #pragma unroll
      for (int i = 0; i < 4; ++i) abuf[nxt][i] = *(const half8_t*)(aBase + aoff + i * 512);
      // compute (priority-boosted)
      __builtin_amdgcn_s_setprio(1);
      #pragma unroll
      for (int i = 0; i < 4; ++i)
        #pragma unroll
        for (int j = 0; j < 8; ++j)
          acc[i][j] = __builtin_amdgcn_mfma_f32_16x16x32_f16(abuf[cur][i], bbuf[j], acc[i][j], 0, 0, 0);
      __builtin_amdgcn_s_setprio(0);
    }

    // epilogue: d' = e2 - 2*dot; per-lane (d1,i1,d2). cw index ascending -> '<' keeps first.
    const int cwb = nc * 256 + wc * 64;
    #pragma unroll
    for (int i = 0; i < 4; ++i) {
      const int cw0 = cwb + i * 16 + quad * 4;    // C/D: row = quad*4 + r (codeword)
      float ee[4];
      #pragma unroll
      for (int r = 0; r < 4; ++r) ee[r] = e2l[cw0 + r];
      #pragma unroll
      for (int j = 0; j < 8; ++j) {
        #pragma unroll
        for (int r = 0; r < 4; ++r) {
          const float d = fmaf(-2.0f, acc[i][j][r], ee[r]);
          const bool lt = d < d1[j];
          const float hi = lt ? d1[j] : d;
          d1[j] = lt ? d : d1[j];
          i1[j] = lt ? (cw0 + r) : i1[j];
          d2[j] = fminf(d2[j], hi);
        }
      }
    }
  }

  // cross-quad butterfly (lanes l, l^16, l^32 share pixel col = lane&15)
  #pragma unroll
  for (int j = 0; j < 8; ++j) {
    #pragma unroll
    for (int m = 16; m <= 32; m <<= 1) {
      const float od1 = __shfl_xor(d1[j], m, 64);
      const int   oi1 = __shfl_xor(i1[j], m, 64);
      const float od2 = __shfl_xor(d2[j], m, 64);
      const bool take = (od1 < d1[j]) || (od1 == d1[j] && oi1 < i1[j]);
      const float hi = take ? d1[j] : od1;
      d1[j] = take ? od1 : d1[j];
      i1[j] = take ? oi1 : i1[j];
      d2[j] = fminf(fminf(d2[j], od2), hi);
    }
  }

  // cross-wave (wc 0..3) merge via LDS (reuse Zl)
  __syncthreads();
  float* rd1  = (float*)Zl;          // [0..1024)
  int*   ri1  = (int*)Zl + 1024;     // [1024..2048)
  float* rd2  = (float*)Zl + 2048;   // [2048..3072)
  float* zsq  = (float*)Zl + 3072;   // [3072..3584)
  float* dsum = (float*)Zl + 3584;   // [3584..3840)
  int*   fid  = (int*)Zl + 3840;     // [3840..4096)
  if (lane < 16) {
    #pragma unroll
    for (int j = 0; j < 8; ++j) {
      const int p = wp * 128 + j * 16 + ln;
      rd1[wc * 256 + p] = d1[j];
      ri1[wc * 256 + p] = i1[j];
      rd2[wc * 256 + p] = d2[j];
    }
  }
  zsq[tid] = s_z2;
  __syncthreads();
  if (tid < 256) {
    float a1 = rd1[tid]; int ai = ri1[tid]; float a2 = rd2[tid];
    #pragma unroll
    for (int m = 1; m < 4; ++m) {
      const float b1 = rd1[m * 256 + tid];
      const int   bi = ri1[m * 256 + tid];
      const float b2 = rd2[m * 256 + tid];
      const bool take = (b1 < a1) || (b1 == a1 && bi < ai);
      const float hi = take ? a1 : b1;
      a1 = take ? b1 : a1;
      ai = take ? bi : ai;
      a2 = fminf(fminf(a2, b2), hi);
    }
    const int gp = ptile + tid;
    fid[tid]  = ai;
    dsum[tid] = a1;
    if ((a2 - a1) <= TAU) {   // fp16 gap error sigma ~3e-2; TAU = 5 sigma
      const int pos = atomicAdd(ccount, 1);
      clist[pos] = gp;
    }
  }
  __syncthreads();
  // block loss partial: Σ_{px} d1 + Σ z²  -> one atomic per block
  if (tid < 64) {
    float v = 0.f;
    #pragma unroll
    for (int k = 0; k < 8; ++k) v += zsq[tid + k * 64];
    #pragma unroll
    for (int k = 0; k < 4; ++k) v += dsum[tid + k * 64];
    #pragma unroll
    for (int off = 32; off; off >>= 1) v += __shfl_down(v, off, 64);
    if (tid == 0) atomicAdd(acc_out, v);
  }
  // fused output write: thread t -> pixel (t&255), channel half (t>>8)*128.
  // Wave lanes = 64 consecutive px at fixed channel -> coalesced 256B stores;
  // cb rows gathered from L2 (1 MB resident).
  {
    const int pl = tid & 255, cs = tid >> 8;
    const int id = fid[pl];
    const float* er = cb + (size_t)id * C_DIM + cs * 128;
    float* orow = out + (size_t)b * (C_DIM * HW) + (size_t)(cs * 128) * HW + pb + pl;
    #pragma unroll 8
    for (int c = 0; c < 128; c += 4) {
      const float4 ev = *(const float4*)(er + c);
      orow[(size_t)(c + 0) * HW] = ev.x;
      orow[(size_t)(c + 1) * HW] = ev.y;
      orow[(size_t)(c + 2) * HW] = ev.z;
      orow[(size_t)(c + 3) * HW] = ev.w;
    }
  }
}

// K2: exact fp32 rescan. One block per group of 4 contested pixels, all 1024
// codewords in-block. fma chain per (cw,px) bit-identical to prior passing
// version. After the argmin, each wave rewrites the out row for its pixel.
// Block 0 also writes the final loss at START (acc final by stream order).
__global__ __launch_bounds__(256)
void rescan_kernel(const float* __restrict__ z, const float* __restrict__ cb,
                   const float* __restrict__ e2, const int* __restrict__ clist,
                   const int* __restrict__ ccount, float* __restrict__ out,
                   const float* __restrict__ acc, float* __restrict__ loss_out) {
  if (blockIdx.x == 0 && threadIdx.x == 0)
    *loss_out = 1.25f * (*acc) * (1.0f / 16777216.0f);
  __shared__ __align__(16) float zl[4][C_DIM];    // [px][k] -> float4 broadcast reads
  __shared__ int pxs[4];
  __shared__ unsigned long long bestk[4];
  const int n = *ccount;
  const int ngroups = (n + 3) >> 2;
  for (int g = blockIdx.x; g < ngroups; g += gridDim.x) {
    const int base = g * 4;
    if ((int)threadIdx.x < 4) {
      pxs[threadIdx.x] = clist[min(base + (int)threadIdx.x, n - 1)];  // pad w/ dup (idempotent)
      bestk[threadIdx.x] = ~0ULL;
    }
    __syncthreads();
    {
      const int k = threadIdx.x;
      #pragma unroll
      for (int i = 0; i < 4; ++i) {
        const int gp = pxs[i];
        zl[i][k] = z[(size_t)(gp >> 12) * (C_DIM * HW) + (size_t)k * HW + (gp & 4095)];
      }
    }
    __syncthreads();
    unsigned long long mykey[4] = {~0ULL, ~0ULL, ~0ULL, ~0ULL};
    #pragma unroll 1
    for (int o = 0; o < 4; ++o) {
      const int cw = o * 256 + (int)threadIdx.x;
      const float* row = cb + (size_t)cw * C_DIM;
      float dot[4] = {0.f, 0.f, 0.f, 0.f};
      #pragma unroll 4
      for (int k0 = 0; k0 < C_DIM; k0 += 4) {
        const float4 ev = *(const float4*)(row + k0);   // coalesced-by-row, L2-hot
        #pragma unroll
        for (int i = 0; i < 4; ++i) {
          const float4 zz = *(const float4*)&zl[i][k0]; // uniform addr -> LDS broadcast
          dot[i] = fmaf(ev.x, zz.x, dot[i]);
          dot[i] = fmaf(ev.y, zz.y, dot[i]);
          dot[i] = fmaf(ev.z, zz.z, dot[i]);
          dot[i] = fmaf(ev.w, zz.w, dot[i]);
        }
      }
      const float ee = e2[cw];
      #pragma unroll
      for (int i = 0; i < 4; ++i) {
        const float d = fmaf(-2.0f, dot[i], ee);
        const unsigned long long key = ((unsigned long long)fenc(d) << 32) | (unsigned)cw;
        mykey[i] = key < mykey[i] ? key : mykey[i];
      }
    }
    // wave-level u64 min reduce, then 1 shared atomic per wave per pixel
    #pragma unroll
    for (int i = 0; i < 4; ++i) {
      unsigned long long k = mykey[i];
      #pragma unroll
      for (int off = 32; off; off >>= 1) {
        const unsigned long long ok = __shfl_xor(k, off, 64);
        k = ok < k ? ok : k;
      }
      if ((threadIdx.x & 63) == 0) atomicMin(&bestk[i], k);
    }
    __syncthreads();
    // rewrite out row for this wave's pixel (duplicate-padded px: identical writes)
    {
      const int i = (int)threadIdx.x >> 6;
      const int l = (int)threadIdx.x & 63;
      const int gp = pxs[i];
      const int id = (int)(unsigned)(bestk[i] & 0xFFFFFFFFull);
      const float* er = cb + (size_t)id * C_DIM;
      float* orow = out + (size_t)(gp >> 12) * (C_DIM * HW) + (gp & 4095);
      const float4 ev = *(const float4*)(er + l * 4);   // coalesced row read
      orow[(size_t)(l * 4 + 0) * HW] = ev.x;
      orow[(size_t)(l * 4 + 1) * HW] = ev.y;
      orow[(size_t)(l * 4 + 2) * HW] = ev.z;
      orow[(size_t)(l * 4 + 3) * HW] = ev.w;
    }
    __syncthreads();
  }
}

extern "C" void kernel_launch(void* const* d_in, const int* in_sizes, int n_in,
                              void* d_out, int out_size, void* d_ws, size_t ws_size,
                              hipStream_t stream) {
  const float* z  = (const float*)d_in[0];
  const float* cb = (const float*)d_in[1];
  float* out = (float*)d_out;
  char* ws = (char*)d_ws;

  float*    acc    = (float*)ws;
  int*      ccount = (int*)(ws + 8);
  float*    e2     = (float*)(ws + 4096);
  _Float16* EhfP   = (_Float16*)(ws + 8192);
  int*      clist  = (int*)(ws + 532480);

  prep_kernel<<<384, 256, 0, stream>>>(cb, EhfP, e2, acc, ccount);
  screen_kernel<<<NPIX / 256, 512, 0, stream>>>(z, EhfP, e2, cb, clist, ccount, acc, out);
  rescan_kernel<<<1024, 256, 0, stream>>>(z, cb, e2, clist, ccount, out, acc,
                                          out + 16777216);
}

// Round 9
// 262.252 us; speedup vs baseline: 1.2578x; 1.2578x over previous
//
#include <hip/hip_runtime.h>
#include <cfloat>

#define C_DIM 256
#define HW    4096
#define NE    1024
#define NPIX  65536
#define TAU   0.15f
#define ZSTR  264   // fp16 per Z-LDS pixel row: 256 ch + 8 pad (528 B, 16B-aligned)

typedef __attribute__((ext_vector_type(8))) _Float16 half8_t;
typedef __attribute__((ext_vector_type(4))) float floatx4;

// monotone float -> uint32 (for packed (d,idx) u64 min with lowest-index tie-break)
__device__ __forceinline__ unsigned int fenc(float f) {
  unsigned int u = __float_as_uint(f);
  return (u & 0x80000000u) ? ~u : (u | 0x80000000u);
}

// ---------------- ws layout ----------------
// @0       float acc (Σ d1 + Σ z², loss numerator)  [zeroed by prep]
// @8       int   ccount                             [zeroed by prep]
// @4096    float e2[1024]
// @8192    _Float16 EhfP[1024*256]     (512 KiB fp16 codebook, MFMA-fragment-packed)
// @532480  int   clist[65536]          (256 KiB, ends 794624)

// K0 (fused): blocks [0,128) pack codebook into MFMA A-fragment order;
// blocks [128,384) compute ||e||^2 per codeword (one wave per codeword).
// Block 128 additionally zeroes acc/ccount.
__global__ __launch_bounds__(256)
void prep_kernel(const float* __restrict__ cb, _Float16* __restrict__ EhfP,
                 float* __restrict__ e2, float* __restrict__ acc,
                 int* __restrict__ ccount) {
  if (blockIdx.x < 128) {
    const int g = blockIdx.x >> 3, it = blockIdx.x & 7;
    const int sidx = it * 256 + (int)threadIdx.x;       // (ks*256 + i*64 + lane)
    const int ks = sidx >> 8, i = (sidx >> 6) & 3, lane = sidx & 63;
    const int ln = lane & 15, quad = lane >> 4;
    const float* src = cb + (size_t)(g * 64 + i * 16 + ln) * C_DIM + ks * 32 + quad * 8;
    const float4 v0 = *(const float4*)(src);
    const float4 v1 = *(const float4*)(src + 4);
    half8_t h;
    h[0] = (_Float16)v0.x; h[1] = (_Float16)v0.y; h[2] = (_Float16)v0.z; h[3] = (_Float16)v0.w;
    h[4] = (_Float16)v1.x; h[5] = (_Float16)v1.y; h[6] = (_Float16)v1.z; h[7] = (_Float16)v1.w;
    *(half8_t*)(EhfP + (size_t)g * 16384 + (size_t)sidx * 8) = h;
  } else {
    if (blockIdx.x == 128 && threadIdx.x == 0) { acc[0] = 0.f; ccount[0] = 0; }
    const int bid = blockIdx.x - 128;
    const int wave = (bid * 256 + (int)threadIdx.x) >> 6;
    const int lane = threadIdx.x & 63;
    const float4 v = *(const float4*)(cb + (size_t)wave * C_DIM + lane * 4);
    float s = v.x * v.x + v.y * v.y + v.z * v.z + v.w * v.w;
    #pragma unroll
    for (int off = 32; off; off >>= 1) s += __shfl_down(s, off, 64);
    if (lane == 0) e2[wave] = s;
  }
}

// K1: fp16 MFMA screen, 128-px tile / 4-wave block (R7 shell). NEW wave decomp:
// wave w = 32 cw x 128 px (acc[2][8], 64 VGPR — same budget as R7's 4x4).
// The 4 waves cover DISJOINT 32-cw slices of each 128-cw chunk (no wp duplicate):
// per ks-step 16 MFMA per 2 A-loads (was 16/4) -> 2x A-load latency tolerance;
// block A-traffic halves (1MB -> 512KB). R8 lesson: __launch_bounds__ 2nd arg is
// min BLOCKS/CU (CUDA semantics) — (256,2) => 8 waves/CU => 256-VGPR cap, no spill
// at the ~210-reg working set.
__global__ __launch_bounds__(256, 2)
void screen_kernel(const float* __restrict__ z, const _Float16* __restrict__ EhfP,
                   const float* __restrict__ e2, const float* __restrict__ cb,
                   int* __restrict__ clist, int* __restrict__ ccount,
                   float* __restrict__ acc_out, float* __restrict__ out) {
  __shared__ __align__(16) _Float16 Zl[128 * ZSTR];   // 67584 B
  __shared__ float e2l[NE];                           // 4096 B

  const int tid = threadIdx.x;
  const int ptile = blockIdx.x * 128;
  const int b = ptile >> 12, pb = ptile & 4095;
  const float* zb = z + (size_t)b * (C_DIM * HW) + pb;

  // stage Z: z[k][p] fp32 -> Zl[p][k] fp16; accumulate Σz² in fp32 on the side.
  float s_z2 = 0.f;
  #pragma unroll
  for (int it = 0; it < 16; ++it) {
    const int flat = it * 256 + tid;
    const int p = flat & 127, kb = flat >> 7;
    float f[8];
    #pragma unroll
    for (int j = 0; j < 8; ++j) f[j] = zb[(size_t)(kb * 8 + j) * HW + p];
    half8_t h;
    #pragma unroll
    for (int j = 0; j < 8; ++j) { s_z2 = fmaf(f[j], f[j], s_z2); h[j] = (_Float16)f[j]; }
    *(half8_t*)&Zl[p * ZSTR + kb * 8] = h;
  }
  #pragma unroll
  for (int i = 0; i < 4; ++i) e2l[i * 256 + tid] = e2[i * 256 + tid];
  __syncthreads();

  const int lane = tid & 63;
  const int w = tid >> 6;          // 4 waves, each a 32-cw slice x 128 px
  const int ln = lane & 15, quad = lane >> 4;

  // A stream: chunk nc = 128 cw = fragment groups {nc*2, nc*2+1}. Wave w owns
  // cw slice nc*128 + w*32 -> group (w>>1), fragments (w&1)*2 + {0,1}.
  // Step s: + (s>>3)*32768 + (s&7)*2048 halves; per-lane +lane*8 (16B, coalesced).
  const _Float16* aBase = EhfP + (size_t)(w >> 1) * 16384 + (size_t)(w & 1) * 1024
                               + (size_t)lane * 8;
  const char* rowB[8];
  #pragma unroll
  for (int j = 0; j < 8; ++j)
    rowB[j] = (const char*)(&Zl[(j * 16 + ln) * ZSTR + quad * 8]);

  float d1[8], d2[8]; int i1[8];
  #pragma unroll
  for (int j = 0; j < 8; ++j) { d1[j] = FLT_MAX; d2[j] = FLT_MAX; i1[j] = 0; }

  half8_t abuf[2][2], bbuf[2][8];
  // prologue: fragments for step 0
  #pragma unroll
  for (int i = 0; i < 2; ++i) abuf[0][i] = *(const half8_t*)(aBase + i * 512);
  #pragma unroll
  for (int j = 0; j < 8; ++j) bbuf[0][j] = *(const half8_t*)(rowB[j]);

  for (int nc = 0; nc < 8; ++nc) {
    floatx4 acc[2][8];
    #pragma unroll
    for (int i = 0; i < 2; ++i)
      #pragma unroll
      for (int j = 0; j < 8; ++j) acc[i][j] = (floatx4){0.f, 0.f, 0.f, 0.f};

    #pragma unroll
    for (int ks = 0; ks < 8; ++ks) {
      const int s = nc * 8 + ks;
      const int cur = ks & 1, nxt = cur ^ 1;
      // prefetch step s+1 (clamped to last step: redundant reload, in-bounds)
      const int sp = s + 1 > 63 ? 63 : s + 1;
      const size_t aoff = (size_t)(sp >> 3) * 32768 + (size_t)(sp & 7) * 2048;
      const int bks = sp & 7;
      #pragma unroll
      for (int i = 0; i < 2; ++i) abuf[nxt][i] = *(const half8_t*)(aBase + aoff + i * 512);
      #pragma unroll
      for (int j = 0; j < 8; ++j) bbuf[nxt][j] = *(const half8_t*)(rowB[j] + bks * 64);
      // compute (priority-boosted)
      __builtin_amdgcn_s_setprio(1);
      #pragma unroll
      for (int i = 0; i < 2; ++i)
        #pragma unroll
        for (int j = 0; j < 8; ++j)
          acc[i][j] = __builtin_amdgcn_mfma_f32_16x16x32_f16(abuf[cur][i], bbuf[cur][j], acc[i][j], 0, 0, 0);
      __builtin_amdgcn_s_setprio(0);
    }

    // epilogue: d' = e2 - 2*dot; per-lane (d1,i1,d2). cw index ascending -> '<' keeps first.
    const int cwb = nc * 128 + w * 32;
    #pragma unroll
    for (int i = 0; i < 2; ++i) {
      const int cw0 = cwb + i * 16 + quad * 4;    // C/D: row = quad*4 + r (codeword)
      float ee[4];
      #pragma unroll
      for (int r = 0; r < 4; ++r) ee[r] = e2l[cw0 + r];
      #pragma unroll
      for (int j = 0; j < 8; ++j) {
        #pragma unroll
        for (int r = 0; r < 4; ++r) {
          const float d = fmaf(-2.0f, acc[i][j][r], ee[r]);
          const bool lt = d < d1[j];
          const float hi = lt ? d1[j] : d;
          d1[j] = lt ? d : d1[j];
          i1[j] = lt ? (cw0 + r) : i1[j];
          d2[j] = fminf(d2[j], hi);
        }
      }
    }
  }

  // cross-quad butterfly (lanes l, l^16, l^32 share pixel col = lane&15)
  #pragma unroll
  for (int j = 0; j < 8; ++j) {
    #pragma unroll
    for (int m = 16; m <= 32; m <<= 1) {
      const float od1 = __shfl_xor(d1[j], m, 64);
      const int   oi1 = __shfl_xor(i1[j], m, 64);
      const float od2 = __shfl_xor(d2[j], m, 64);
      const bool take = (od1 < d1[j]) || (od1 == d1[j] && oi1 < i1[j]);
      const float hi = take ? d1[j] : od1;
      d1[j] = take ? od1 : d1[j];
      i1[j] = take ? oi1 : i1[j];
      d2[j] = fminf(fminf(d2[j], od2), hi);
    }
  }

  // cross-wave merge via LDS (reuse Zl): 4 cw-partitions per pixel (R8-verified
  // 4-way merge shape, adapted to 128 px).
  __syncthreads();
  float* rd1  = (float*)Zl;          // [0..512)
  int*   ri1  = (int*)Zl + 512;      // [512..1024)
  float* rd2  = (float*)Zl + 1024;   // [1024..1536)
  float* zsq  = (float*)Zl + 1536;   // [1536..1792)
  float* dsum = (float*)Zl + 1792;   // [1792..1920)
  int*   fid  = (int*)Zl + 1920;     // [1920..2048)
  if (lane < 16) {
    #pragma unroll
    for (int j = 0; j < 8; ++j) {
      const int p = j * 16 + ln;
      rd1[w * 128 + p] = d1[j];
      ri1[w * 128 + p] = i1[j];
      rd2[w * 128 + p] = d2[j];
    }
  }
  zsq[tid] = s_z2;
  __syncthreads();
  if (tid < 128) {
    float a1 = rd1[tid]; int ai = ri1[tid]; float a2 = rd2[tid];
    #pragma unroll
    for (int m = 1; m < 4; ++m) {
      const float b1 = rd1[m * 128 + tid];
      const int   bi = ri1[m * 128 + tid];
      const float b2 = rd2[m * 128 + tid];
      const bool take = (b1 < a1) || (b1 == a1 && bi < ai);
      const float hi = take ? a1 : b1;
      a1 = take ? b1 : a1;
      ai = take ? bi : ai;
      a2 = fminf(fminf(a2, b2), hi);
    }
    const int gp = ptile + tid;
    fid[tid]  = ai;
    dsum[tid] = a1;
    if ((a2 - a1) <= TAU) {   // fp16 gap error sigma ~3e-2; TAU = 5 sigma
      const int pos = atomicAdd(ccount, 1);
      clist[pos] = gp;
    }
  }
  __syncthreads();
  // block loss partial: Σ_{px} d1 + Σ z²  -> one atomic per block
  if (tid < 64) {
    float v = zsq[tid] + zsq[tid + 64] + zsq[tid + 128] + zsq[tid + 192]
            + dsum[tid] + dsum[tid + 64];
    #pragma unroll
    for (int off = 32; off; off >>= 1) v += __shfl_down(v, off, 64);
    if (tid == 0) atomicAdd(acc_out, v);
  }
  // fused output write: thread t -> pixel (t&127), channel half (t>>7)*128.
  // Wave lanes = 64 consecutive px at fixed channel -> coalesced 256B stores;
  // cb rows gathered from L2 (1 MB resident).
  {
    const int pl = tid & 127, cs = tid >> 7;
    const int id = fid[pl];
    const float* er = cb + (size_t)id * C_DIM + cs * 128;
    float* orow = out + (size_t)b * (C_DIM * HW) + (size_t)(cs * 128) * HW + pb + pl;
    #pragma unroll 8
    for (int c = 0; c < 128; c += 4) {
      const float4 ev = *(const float4*)(er + c);
      orow[(size_t)(c + 0) * HW] = ev.x;
      orow[(size_t)(c + 1) * HW] = ev.y;
      orow[(size_t)(c + 2) * HW] = ev.z;
      orow[(size_t)(c + 3) * HW] = ev.w;
    }
  }
}

// K2: exact fp32 rescan. One block per group of 4 contested pixels, all 1024
// codewords in-block. fma chain per (cw,px) bit-identical to prior passing
// version. After the argmin, each wave rewrites the out row for its pixel.
// Block 0 also writes the final loss at START (acc final by stream order).
__global__ __launch_bounds__(256)
void rescan_kernel(const float* __restrict__ z, const float* __restrict__ cb,
                   const float* __restrict__ e2, const int* __restrict__ clist,
                   const int* __restrict__ ccount, float* __restrict__ out,
                   const float* __restrict__ acc, float* __restrict__ loss_out) {
  if (blockIdx.x == 0 && threadIdx.x == 0)
    *loss_out = 1.25f * (*acc) * (1.0f / 16777216.0f);
  __shared__ __align__(16) float zl[4][C_DIM];    // [px][k] -> float4 broadcast reads
  __shared__ int pxs[4];
  __shared__ unsigned long long bestk[4];
  const int n = *ccount;
  const int ngroups = (n + 3) >> 2;
  for (int g = blockIdx.x; g < ngroups; g += gridDim.x) {
    const int base = g * 4;
    if ((int)threadIdx.x < 4) {
      pxs[threadIdx.x] = clist[min(base + (int)threadIdx.x, n - 1)];  // pad w/ dup (idempotent)
      bestk[threadIdx.x] = ~0ULL;
    }
    __syncthreads();
    {
      const int k = threadIdx.x;
      #pragma unroll
      for (int i = 0; i < 4; ++i) {
        const int gp = pxs[i];
        zl[i][k] = z[(size_t)(gp >> 12) * (C_DIM * HW) + (size_t)k * HW + (gp & 4095)];
      }
    }
    __syncthreads();
    unsigned long long mykey[4] = {~0ULL, ~0ULL, ~0ULL, ~0ULL};
    #pragma unroll 1
    for (int o = 0; o < 4; ++o) {
      const int cw = o * 256 + (int)threadIdx.x;
      const float* row = cb + (size_t)cw * C_DIM;
      float dot[4] = {0.f, 0.f, 0.f, 0.f};
      #pragma unroll 4
      for (int k0 = 0; k0 < C_DIM; k0 += 4) {
        const float4 ev = *(const float4*)(row + k0);   // coalesced-by-row, L2-hot
        #pragma unroll
        for (int i = 0; i < 4; ++i) {
          const float4 zz = *(const float4*)&zl[i][k0]; // uniform addr -> LDS broadcast
          dot[i] = fmaf(ev.x, zz.x, dot[i]);
          dot[i] = fmaf(ev.y, zz.y, dot[i]);
          dot[i] = fmaf(ev.z, zz.z, dot[i]);
          dot[i] = fmaf(ev.w, zz.w, dot[i]);
        }
      }
      const float ee = e2[cw];
      #pragma unroll
      for (int i = 0; i < 4; ++i) {
        const float d = fmaf(-2.0f, dot[i], ee);
        const unsigned long long key = ((unsigned long long)fenc(d) << 32) | (unsigned)cw;
        mykey[i] = key < mykey[i] ? key : mykey[i];
      }
    }
    // wave-level u64 min reduce, then 1 shared atomic per wave per pixel
    #pragma unroll
    for (int i = 0; i < 4; ++i) {
      unsigned long long k = mykey[i];
      #pragma unroll
      for (int off = 32; off; off >>= 1) {
        const unsigned long long ok = __shfl_xor(k, off, 64);
        k = ok < k ? ok : k;
      }
      if ((threadIdx.x & 63) == 0) atomicMin(&bestk[i], k);
    }
    __syncthreads();
    // rewrite out row for this wave's pixel (duplicate-padded px: identical writes)
    {
      const int i = (int)threadIdx.x >> 6;
      const int l = (int)threadIdx.x & 63;
      const int gp = pxs[i];
      const int id = (int)(unsigned)(bestk[i] & 0xFFFFFFFFull);
      const float* er = cb + (size_t)id * C_DIM;
      float* orow = out + (size_t)(gp >> 12) * (C_DIM * HW) + (gp & 4095);
      const float4 ev = *(const float4*)(er + l * 4);   // coalesced row read
      orow[(size_t)(l * 4 + 0) * HW] = ev.x;
      orow[(size_t)(l * 4 + 1) * HW] = ev.y;
      orow[(size_t)(l * 4 + 2) * HW] = ev.z;
      orow[(size_t)(l * 4 + 3) * HW] = ev.w;
    }
    __syncthreads();
  }
}

extern "C" void kernel_launch(void* const* d_in, const int* in_sizes, int n_in,
                              void* d_out, int out_size, void* d_ws, size_t ws_size,
                              hipStream_t stream) {
  const float* z  = (const float*)d_in[0];
  const float* cb = (const float*)d_in[1];
  float* out = (float*)d_out;
  char* ws = (char*)d_ws;

  float*    acc    = (float*)ws;
  int*      ccount = (int*)(ws + 8);
  float*    e2     = (float*)(ws + 4096);
  _Float16* EhfP   = (_Float16*)(ws + 8192);
  int*      clist  = (int*)(ws + 532480);

  prep_kernel<<<384, 256, 0, stream>>>(cb, EhfP, e2, acc, ccount);
  screen_kernel<<<NPIX / 128, 256, 0, stream>>>(z, EhfP, e2, cb, clist, ccount, acc, out);
  rescan_kernel<<<1024, 256, 0, stream>>>(z, cb, e2, clist, ccount, out, acc,
                                          out + 16777216);
}

// Round 10
// 199.812 us; speedup vs baseline: 1.6508x; 1.3125x over previous
//
#include <hip/hip_runtime.h>
#include <cfloat>

#define C_DIM 256
#define HW    4096
#define NE    1024
#define NPIX  65536
#define TAU   0.15f
#define ZSTR  264   // fp16 per Z-LDS pixel row: 256 ch + 8 pad (528 B, 16B-aligned)

typedef __attribute__((ext_vector_type(8))) _Float16 half8_t;
typedef __attribute__((ext_vector_type(4))) float floatx4;

// monotone float -> uint32 (for packed (d,idx) u64 min with lowest-index tie-break)
__device__ __forceinline__ unsigned int fenc(float f) {
  unsigned int u = __float_as_uint(f);
  return (u & 0x80000000u) ? ~u : (u | 0x80000000u);
}

// ---------------- ws layout ----------------
// @0       float acc (Σ d1 + Σ z², loss numerator)  [zeroed by prep]
// @8       int   ccount                             [zeroed by prep]
// @4096    float e2[1024]
// @8192    _Float16 EhfP[1024*256]     (512 KiB fp16 codebook, MFMA-fragment-packed)
// @532480  int   clist[65536]          (256 KiB, ends 794624)

// K0 (fused): blocks [0,128) pack codebook into MFMA A-fragment order;
// blocks [128,384) compute ||e||^2 per codeword (one wave per codeword).
// Block 128 additionally zeroes acc/ccount.
__global__ __launch_bounds__(256)
void prep_kernel(const float* __restrict__ cb, _Float16* __restrict__ EhfP,
                 float* __restrict__ e2, float* __restrict__ acc,
                 int* __restrict__ ccount) {
  if (blockIdx.x < 128) {
    const int g = blockIdx.x >> 3, it = blockIdx.x & 7;
    const int sidx = it * 256 + (int)threadIdx.x;       // (ks*256 + i*64 + lane)
    const int ks = sidx >> 8, i = (sidx >> 6) & 3, lane = sidx & 63;
    const int ln = lane & 15, quad = lane >> 4;
    const float* src = cb + (size_t)(g * 64 + i * 16 + ln) * C_DIM + ks * 32 + quad * 8;
    const float4 v0 = *(const float4*)(src);
    const float4 v1 = *(const float4*)(src + 4);
    half8_t h;
    h[0] = (_Float16)v0.x; h[1] = (_Float16)v0.y; h[2] = (_Float16)v0.z; h[3] = (_Float16)v0.w;
    h[4] = (_Float16)v1.x; h[5] = (_Float16)v1.y; h[6] = (_Float16)v1.z; h[7] = (_Float16)v1.w;
    *(half8_t*)(EhfP + (size_t)g * 16384 + (size_t)sidx * 8) = h;
  } else {
    if (blockIdx.x == 128 && threadIdx.x == 0) { acc[0] = 0.f; ccount[0] = 0; }
    const int bid = blockIdx.x - 128;
    const int wave = (bid * 256 + (int)threadIdx.x) >> 6;
    const int lane = threadIdx.x & 63;
    const float4 v = *(const float4*)(cb + (size_t)wave * C_DIM + lane * 4);
    float s = v.x * v.x + v.y * v.y + v.z * v.z + v.w * v.w;
    #pragma unroll
    for (int off = 32; off; off >>= 1) s += __shfl_down(s, off, 64);
    if (lane == 0) e2[wave] = s;
  }
}

// K1: fp16 MFMA screen. SAME 128-px tile / LDS (2 blocks/CU) as R7, but 8 waves
// per block (512 threads): wave = 32 cw x 64 px (wc = cw-quarter, wp = px-half).
// Identical A/z/write traffic (wp pairs re-read same A lines -> L1 hits), but
// 16 waves/CU (4/SIMD) = 2x TLP vs R7 — attacks the measured latency-bound
// regime (both pipes ~25% busy, occupancy 18%). Register model (R8/R9 lesson):
// arch-VGPR budget is ~128 with accumulators in AGPRs; this config's arch set
// = abuf 16 + bbuf 32 + misc ~45 + stage-overlap ≈ 110 < 128 (acc[2][4]=32 AGPR).
__global__ __launch_bounds__(512, 2)
void screen_kernel(const float* __restrict__ z, const _Float16* __restrict__ EhfP,
                   const float* __restrict__ e2, const float* __restrict__ cb,
                   int* __restrict__ clist, int* __restrict__ ccount,
                   float* __restrict__ acc_out, float* __restrict__ out) {
  __shared__ __align__(16) _Float16 Zl[128 * ZSTR];   // 67584 B
  __shared__ float e2l[NE];                           // 4096 B

  const int tid = threadIdx.x;
  const int ptile = blockIdx.x * 128;
  const int b = ptile >> 12, pb = ptile & 4095;
  const float* zb = z + (size_t)b * (C_DIM * HW) + pb;

  // stage Z: z[k][p] fp32 -> Zl[p][k] fp16; accumulate Σz² in fp32 on the side.
  float s_z2 = 0.f;
  #pragma unroll
  for (int it = 0; it < 8; ++it) {
    const int flat = it * 512 + tid;
    const int p = flat & 127, kb = flat >> 7;
    float f[8];
    #pragma unroll
    for (int j = 0; j < 8; ++j) f[j] = zb[(size_t)(kb * 8 + j) * HW + p];
    half8_t h;
    #pragma unroll
    for (int j = 0; j < 8; ++j) { s_z2 = fmaf(f[j], f[j], s_z2); h[j] = (_Float16)f[j]; }
    *(half8_t*)&Zl[p * ZSTR + kb * 8] = h;
  }
  #pragma unroll
  for (int i = 0; i < 2; ++i) e2l[i * 512 + tid] = e2[i * 512 + tid];
  __syncthreads();

  const int lane = tid & 63;
  const int w = tid >> 6;          // 8 waves
  const int wc = w & 3, wp = w >> 2;
  const int ln = lane & 15, quad = lane >> 4;

  // A stream: chunk nc = 128 cw = fragment groups {nc*2, nc*2+1}. Wave's cw
  // slice nc*128 + wc*32 -> group (wc>>1), fragments (wc&1)*2 + {0,1}.
  // Step s: + (s>>3)*32768 + (s&7)*2048 halves; per-lane +lane*8 (16B, coalesced).
  const _Float16* aBase = EhfP + (size_t)(wc >> 1) * 16384 + (size_t)(wc & 1) * 1024
                               + (size_t)lane * 8;
  const char* rowB[4];
  #pragma unroll
  for (int j = 0; j < 4; ++j)
    rowB[j] = (const char*)(&Zl[(wp * 64 + j * 16 + ln) * ZSTR + quad * 8]);

  float d1[4], d2[4]; int i1[4];
  #pragma unroll
  for (int j = 0; j < 4; ++j) { d1[j] = FLT_MAX; d2[j] = FLT_MAX; i1[j] = 0; }

  half8_t abuf[2][2], bbuf[2][4];
  // prologue: fragments for step 0
  #pragma unroll
  for (int i = 0; i < 2; ++i) abuf[0][i] = *(const half8_t*)(aBase + i * 512);
  #pragma unroll
  for (int j = 0; j < 4; ++j) bbuf[0][j] = *(const half8_t*)(rowB[j]);

  for (int nc = 0; nc < 8; ++nc) {
    floatx4 acc[2][4];
    #pragma unroll
    for (int i = 0; i < 2; ++i)
      #pragma unroll
      for (int j = 0; j < 4; ++j) acc[i][j] = (floatx4){0.f, 0.f, 0.f, 0.f};

    #pragma unroll
    for (int ks = 0; ks < 8; ++ks) {
      const int s = nc * 8 + ks;
      const int cur = ks & 1, nxt = cur ^ 1;
      // prefetch step s+1 (clamped to last step: redundant reload, in-bounds)
      const int sp = s + 1 > 63 ? 63 : s + 1;
      const size_t aoff = (size_t)(sp >> 3) * 32768 + (size_t)(sp & 7) * 2048;
      const int bks = sp & 7;
      #pragma unroll
      for (int i = 0; i < 2; ++i) abuf[nxt][i] = *(const half8_t*)(aBase + aoff + i * 512);
      #pragma unroll
      for (int j = 0; j < 4; ++j) bbuf[nxt][j] = *(const half8_t*)(rowB[j] + bks * 64);
      // compute (priority-boosted)
      __builtin_amdgcn_s_setprio(1);
      #pragma unroll
      for (int i = 0; i < 2; ++i)
        #pragma unroll
        for (int j = 0; j < 4; ++j)
          acc[i][j] = __builtin_amdgcn_mfma_f32_16x16x32_f16(abuf[cur][i], bbuf[cur][j], acc[i][j], 0, 0, 0);
      __builtin_amdgcn_s_setprio(0);
    }

    // epilogue: d' = e2 - 2*dot; per-lane (d1,i1,d2). cw index ascending -> '<' keeps first.
    const int cwb = nc * 128 + wc * 32;
    #pragma unroll
    for (int i = 0; i < 2; ++i) {
      const int cw0 = cwb + i * 16 + quad * 4;    // C/D: row = quad*4 + r (codeword)
      float ee[4];
      #pragma unroll
      for (int r = 0; r < 4; ++r) ee[r] = e2l[cw0 + r];
      #pragma unroll
      for (int j = 0; j < 4; ++j) {
        #pragma unroll
        for (int r = 0; r < 4; ++r) {
          const float d = fmaf(-2.0f, acc[i][j][r], ee[r]);
          const bool lt = d < d1[j];
          const float hi = lt ? d1[j] : d;
          d1[j] = lt ? d : d1[j];
          i1[j] = lt ? (cw0 + r) : i1[j];
          d2[j] = fminf(d2[j], hi);
        }
      }
    }
  }

  // cross-quad butterfly (lanes l, l^16, l^32 share pixel col = lane&15)
  #pragma unroll
  for (int j = 0; j < 4; ++j) {
    #pragma unroll
    for (int m = 16; m <= 32; m <<= 1) {
      const float od1 = __shfl_xor(d1[j], m, 64);
      const int   oi1 = __shfl_xor(i1[j], m, 64);
      const float od2 = __shfl_xor(d2[j], m, 64);
      const bool take = (od1 < d1[j]) || (od1 == d1[j] && oi1 < i1[j]);
      const float hi = take ? d1[j] : od1;
      d1[j] = take ? od1 : d1[j];
      i1[j] = take ? oi1 : i1[j];
      d2[j] = fminf(fminf(d2[j], od2), hi);
    }
  }

  // cross-wave merge via LDS (reuse Zl): 4 cw-partitions per pixel (R8/R9-verified
  // 4-way merge; index tie-break is partition-order-independent). wp halves fill
  // disjoint 64-px ranges of each partition row.
  __syncthreads();
  float* rd1  = (float*)Zl;          // [0..512)
  int*   ri1  = (int*)Zl + 512;      // [512..1024)
  float* rd2  = (float*)Zl + 1024;   // [1024..1536)
  float* zsq  = (float*)Zl + 1536;   // [1536..2048)
  float* dsum = (float*)Zl + 2048;   // [2048..2176)
  int*   fid  = (int*)Zl + 2176;     // [2176..2304)
  if (lane < 16) {
    #pragma unroll
    for (int j = 0; j < 4; ++j) {
      const int p = wp * 64 + j * 16 + ln;
      rd1[wc * 128 + p] = d1[j];
      ri1[wc * 128 + p] = i1[j];
      rd2[wc * 128 + p] = d2[j];
    }
  }
  zsq[tid] = s_z2;
  __syncthreads();
  if (tid < 128) {
    float a1 = rd1[tid]; int ai = ri1[tid]; float a2 = rd2[tid];
    #pragma unroll
    for (int m = 1; m < 4; ++m) {
      const float b1 = rd1[m * 128 + tid];
      const int   bi = ri1[m * 128 + tid];
      const float b2 = rd2[m * 128 + tid];
      const bool take = (b1 < a1) || (b1 == a1 && bi < ai);
      const float hi = take ? a1 : b1;
      a1 = take ? b1 : a1;
      ai = take ? bi : ai;
      a2 = fminf(fminf(a2, b2), hi);
    }
    const int gp = ptile + tid;
    fid[tid]  = ai;
    dsum[tid] = a1;
    if ((a2 - a1) <= TAU) {   // fp16 gap error sigma ~3e-2; TAU = 5 sigma
      const int pos = atomicAdd(ccount, 1);
      clist[pos] = gp;
    }
  }
  __syncthreads();
  // block loss partial: Σ_{px} d1 + Σ z²  -> one atomic per block
  if (tid < 64) {
    float v = 0.f;
    #pragma unroll
    for (int k = 0; k < 8; ++k) v += zsq[tid + k * 64];
    v += dsum[tid] + dsum[tid + 64];
    #pragma unroll
    for (int off = 32; off; off >>= 1) v += __shfl_down(v, off, 64);
    if (tid == 0) atomicAdd(acc_out, v);
  }
  // fused output write: thread t -> pixel (t&127), channel quarter (t>>7)*64.
  // Wave lanes = 64 consecutive px at fixed channel -> coalesced 256B stores;
  // cb rows gathered from L2 (1 MB resident).
  {
    const int pl = tid & 127, cs = tid >> 7;
    const int id = fid[pl];
    const float* er = cb + (size_t)id * C_DIM + cs * 64;
    float* orow = out + (size_t)b * (C_DIM * HW) + (size_t)(cs * 64) * HW + pb + pl;
    #pragma unroll 8
    for (int c = 0; c < 64; c += 4) {
      const float4 ev = *(const float4*)(er + c);
      orow[(size_t)(c + 0) * HW] = ev.x;
      orow[(size_t)(c + 1) * HW] = ev.y;
      orow[(size_t)(c + 2) * HW] = ev.z;
      orow[(size_t)(c + 3) * HW] = ev.w;
    }
  }
}

// K2: exact fp32 rescan. One block per group of 4 contested pixels, all 1024
// codewords in-block. fma chain per (cw,px) bit-identical to prior passing
// version. After the argmin, each wave rewrites the out row for its pixel.
// Block 0 also writes the final loss at START (acc final by stream order).
__global__ __launch_bounds__(256)
void rescan_kernel(const float* __restrict__ z, const float* __restrict__ cb,
                   const float* __restrict__ e2, const int* __restrict__ clist,
                   const int* __restrict__ ccount, float* __restrict__ out,
                   const float* __restrict__ acc, float* __restrict__ loss_out) {
  if (blockIdx.x == 0 && threadIdx.x == 0)
    *loss_out = 1.25f * (*acc) * (1.0f / 16777216.0f);
  __shared__ __align__(16) float zl[4][C_DIM];    // [px][k] -> float4 broadcast reads
  __shared__ int pxs[4];
  __shared__ unsigned long long bestk[4];
  const int n = *ccount;
  const int ngroups = (n + 3) >> 2;
  for (int g = blockIdx.x; g < ngroups; g += gridDim.x) {
    const int base = g * 4;
    if ((int)threadIdx.x < 4) {
      pxs[threadIdx.x] = clist[min(base + (int)threadIdx.x, n - 1)];  // pad w/ dup (idempotent)
      bestk[threadIdx.x] = ~0ULL;
    }
    __syncthreads();
    {
      const int k = threadIdx.x;
      #pragma unroll
      for (int i = 0; i < 4; ++i) {
        const int gp = pxs[i];
        zl[i][k] = z[(size_t)(gp >> 12) * (C_DIM * HW) + (size_t)k * HW + (gp & 4095)];
      }
    }
    __syncthreads();
    unsigned long long mykey[4] = {~0ULL, ~0ULL, ~0ULL, ~0ULL};
    #pragma unroll 1
    for (int o = 0; o < 4; ++o) {
      const int cw = o * 256 + (int)threadIdx.x;
      const float* row = cb + (size_t)cw * C_DIM;
      float dot[4] = {0.f, 0.f, 0.f, 0.f};
      #pragma unroll 4
      for (int k0 = 0; k0 < C_DIM; k0 += 4) {
        const float4 ev = *(const float4*)(row + k0);   // coalesced-by-row, L2-hot
        #pragma unroll
        for (int i = 0; i < 4; ++i) {
          const float4 zz = *(const float4*)&zl[i][k0]; // uniform addr -> LDS broadcast
          dot[i] = fmaf(ev.x, zz.x, dot[i]);
          dot[i] = fmaf(ev.y, zz.y, dot[i]);
          dot[i] = fmaf(ev.z, zz.z, dot[i]);
          dot[i] = fmaf(ev.w, zz.w, dot[i]);
        }
      }
      const float ee = e2[cw];
      #pragma unroll
      for (int i = 0; i < 4; ++i) {
        const float d = fmaf(-2.0f, dot[i], ee);
        const unsigned long long key = ((unsigned long long)fenc(d) << 32) | (unsigned)cw;
        mykey[i] = key < mykey[i] ? key : mykey[i];
      }
    }
    // wave-level u64 min reduce, then 1 shared atomic per wave per pixel
    #pragma unroll
    for (int i = 0; i < 4; ++i) {
      unsigned long long k = mykey[i];
      #pragma unroll
      for (int off = 32; off; off >>= 1) {
        const unsigned long long ok = __shfl_xor(k, off, 64);
        k = ok < k ? ok : k;
      }
      if ((threadIdx.x & 63) == 0) atomicMin(&bestk[i], k);
    }
    __syncthreads();
    // rewrite out row for this wave's pixel (duplicate-padded px: identical writes)
    {
      const int i = (int)threadIdx.x >> 6;
      const int l = (int)threadIdx.x & 63;
      const int gp = pxs[i];
      const int id = (int)(unsigned)(bestk[i] & 0xFFFFFFFFull);
      const float* er = cb + (size_t)id * C_DIM;
      float* orow = out + (size_t)(gp >> 12) * (C_DIM * HW) + (gp & 4095);
      const float4 ev = *(const float4*)(er + l * 4);   // coalesced row read
      orow[(size_t)(l * 4 + 0) * HW] = ev.x;
      orow[(size_t)(l * 4 + 1) * HW] = ev.y;
      orow[(size_t)(l * 4 + 2) * HW] = ev.z;
      orow[(size_t)(l * 4 + 3) * HW] = ev.w;
    }
    __syncthreads();
  }
}

extern "C" void kernel_launch(void* const* d_in, const int* in_sizes, int n_in,
                              void* d_out, int out_size, void* d_ws, size_t ws_size,
                              hipStream_t stream) {
  const float* z  = (const float*)d_in[0];
  const float* cb = (const float*)d_in[1];
  float* out = (float*)d_out;
  char* ws = (char*)d_ws;

  float*    acc    = (float*)ws;
  int*      ccount = (int*)(ws + 8);
  float*    e2     = (float*)(ws + 4096);
  _Float16* EhfP   = (_Float16*)(ws + 8192);
  int*      clist  = (int*)(ws + 532480);

  prep_kernel<<<384, 256, 0, stream>>>(cb, EhfP, e2, acc, ccount);
  screen_kernel<<<NPIX / 128, 512, 0, stream>>>(z, EhfP, e2, cb, clist, ccount, acc, out);
  rescan_kernel<<<1024, 256, 0, stream>>>(z, cb, e2, clist, ccount, out, acc,
                                          out + 16777216);
}

// Round 11
// 193.679 us; speedup vs baseline: 1.7031x; 1.0317x over previous
//
#include <hip/hip_runtime.h>
#include <cfloat>

#define C_DIM 256
#define HW    4096
#define NE    1024
#define NPIX  65536
#define TAU   0.15f
#define ZSTR  264   // fp16 per Z-LDS pixel row: 256 ch + 8 pad (528 B, 16B-aligned)

typedef __attribute__((ext_vector_type(8))) _Float16 half8_t;
typedef __attribute__((ext_vector_type(4))) float floatx4;

// monotone float -> uint32 (for packed (d,idx) u64 min with lowest-index tie-break)
__device__ __forceinline__ unsigned int fenc(float f) {
  unsigned int u = __float_as_uint(f);
  return (u & 0x80000000u) ? ~u : (u | 0x80000000u);
}

// ---------------- ws layout ----------------
// @0       float acc (Σ d1 + Σ z², loss numerator)  [zeroed by prep]
// @8       int   ccount                             [zeroed by prep]
// @4096    float e2[1024]
// @8192    _Float16 EhfP[1024*256]     (512 KiB fp16 codebook, MFMA-fragment-packed)
// @532480  int   clist[65536]          (256 KiB, ends 794624)

// K0 (fused): blocks [0,128) pack codebook into MFMA A-fragment order;
// blocks [128,384) compute ||e||^2 per codeword (one wave per codeword).
// Block 128 additionally zeroes acc/ccount.
__global__ __launch_bounds__(256)
void prep_kernel(const float* __restrict__ cb, _Float16* __restrict__ EhfP,
                 float* __restrict__ e2, float* __restrict__ acc,
                 int* __restrict__ ccount) {
  if (blockIdx.x < 128) {
    const int g = blockIdx.x >> 3, it = blockIdx.x & 7;
    const int sidx = it * 256 + (int)threadIdx.x;       // (ks*256 + i*64 + lane)
    const int ks = sidx >> 8, i = (sidx >> 6) & 3, lane = sidx & 63;
    const int ln = lane & 15, quad = lane >> 4;
    const float* src = cb + (size_t)(g * 64 + i * 16 + ln) * C_DIM + ks * 32 + quad * 8;
    const float4 v0 = *(const float4*)(src);
    const float4 v1 = *(const float4*)(src + 4);
    half8_t h;
    h[0] = (_Float16)v0.x; h[1] = (_Float16)v0.y; h[2] = (_Float16)v0.z; h[3] = (_Float16)v0.w;
    h[4] = (_Float16)v1.x; h[5] = (_Float16)v1.y; h[6] = (_Float16)v1.z; h[7] = (_Float16)v1.w;
    *(half8_t*)(EhfP + (size_t)g * 16384 + (size_t)sidx * 8) = h;
  } else {
    if (blockIdx.x == 128 && threadIdx.x == 0) { acc[0] = 0.f; ccount[0] = 0; }
    const int bid = blockIdx.x - 128;
    const int wave = (bid * 256 + (int)threadIdx.x) >> 6;
    const int lane = threadIdx.x & 63;
    const float4 v = *(const float4*)(cb + (size_t)wave * C_DIM + lane * 4);
    float s = v.x * v.x + v.y * v.y + v.z * v.z + v.w * v.w;
    #pragma unroll
    for (int off = 32; off; off >>= 1) s += __shfl_down(s, off, 64);
    if (lane == 0) e2[wave] = s;
  }
}

// K1: fp16 MFMA screen — RESTORED R7 configuration (best measured: 66 µs,
// 193.1 µs total). 128-px tile, 4 waves, wave = 64 cw x 64 px (4x4 MFMA grid),
// A/B depth-1 double-buffer, setprio(1) around the MFMA cluster, fused loss
// accumulation + fused output write. Structural ledger: depth-2 prefetch (R1
// null), 64-px tile (R4 -25%), 256-px/8w (R8 spill), j=8 (R9 spill), 128-px/8w
// (R10 -11%, 3x bank conflicts). This structure-class ceiling is ~21% of MFMA
// peak; breaking it needs an 8-phase rework incompatible with the fp32->fp16
// staging conversion.
__global__ __launch_bounds__(256, 2)
void screen_kernel(const float* __restrict__ z, const _Float16* __restrict__ EhfP,
                   const float* __restrict__ e2, const float* __restrict__ cb,
                   int* __restrict__ clist, int* __restrict__ ccount,
                   float* __restrict__ acc_out, float* __restrict__ out) {
  __shared__ __align__(16) _Float16 Zl[128 * ZSTR];   // 67584 B
  __shared__ float e2l[NE];                           // 4096 B

  const int tid = threadIdx.x;
  const int ptile = blockIdx.x * 128;
  const int b = ptile >> 12, pb = ptile & 4095;
  const float* zb = z + (size_t)b * (C_DIM * HW) + pb;

  // stage Z: z[k][p] fp32 -> Zl[p][k] fp16; accumulate Σz² in fp32 on the side.
  float s_z2 = 0.f;
  #pragma unroll
  for (int it = 0; it < 16; ++it) {
    const int flat = it * 256 + tid;
    const int p = flat & 127, kb = flat >> 7;
    float f[8];
    #pragma unroll
    for (int j = 0; j < 8; ++j) f[j] = zb[(size_t)(kb * 8 + j) * HW + p];
    half8_t h;
    #pragma unroll
    for (int j = 0; j < 8; ++j) { s_z2 = fmaf(f[j], f[j], s_z2); h[j] = (_Float16)f[j]; }
    *(half8_t*)&Zl[p * ZSTR + kb * 8] = h;
  }
  #pragma unroll
  for (int i = 0; i < 4; ++i) e2l[i * 256 + tid] = e2[i * 256 + tid];
  __syncthreads();

  const int lane = tid & 63;
  const int w = tid >> 6;
  const int wc = w & 1, wp = w >> 1;
  const int ln = lane & 15, quad = lane >> 4;

  // A stream: wave wc's fragments for chunk nc at EhfP + (nc*2+wc)*16384 halves;
  // step (nc,ks), frag i: + ks*2048 + i*512 + lane*8 halves (16B/lane, coalesced).
  const _Float16* aBase = EhfP + (size_t)wc * 16384 + (size_t)lane * 8;
  const char* rowB[4];
  #pragma unroll
  for (int j = 0; j < 4; ++j)
    rowB[j] = (const char*)(&Zl[(wp * 64 + j * 16 + ln) * ZSTR + quad * 8]);

  float d1[4], d2[4]; int i1[4];
  #pragma unroll
  for (int j = 0; j < 4; ++j) { d1[j] = FLT_MAX; d2[j] = FLT_MAX; i1[j] = 0; }

  half8_t abuf[2][4], bbuf[2][4];
  // prologue: fragments for step 0 (nc=0, ks=0)
  #pragma unroll
  for (int i = 0; i < 4; ++i) abuf[0][i] = *(const half8_t*)(aBase + i * 512);
  #pragma unroll
  for (int j = 0; j < 4; ++j) bbuf[0][j] = *(const half8_t*)(rowB[j]);

  for (int nc = 0; nc < 8; ++nc) {
    floatx4 acc[4][4];
    #pragma unroll
    for (int i = 0; i < 4; ++i)
      #pragma unroll
      for (int j = 0; j < 4; ++j) acc[i][j] = (floatx4){0.f, 0.f, 0.f, 0.f};

    #pragma unroll
    for (int ks = 0; ks < 8; ++ks) {
      const int cur = ks & 1, nxt = cur ^ 1;
      // prefetch step s+1 (clamped to last step: redundant reload, in-bounds)
      const int s1 = nc * 8 + ks + 1;
      const int sp = s1 > 63 ? 63 : s1;
      const size_t aoff = (size_t)(sp >> 3) * 32768 + (size_t)(sp & 7) * 2048;
      const int bks = sp & 7;
      #pragma unroll
      for (int i = 0; i < 4; ++i) abuf[nxt][i] = *(const half8_t*)(aBase + aoff + i * 512);
      #pragma unroll
      for (int j = 0; j < 4; ++j) bbuf[nxt][j] = *(const half8_t*)(rowB[j] + bks * 64);
      // compute on current buffers (priority-boosted)
      __builtin_amdgcn_s_setprio(1);
      #pragma unroll
      for (int i = 0; i < 4; ++i)
        #pragma unroll
        for (int j = 0; j < 4; ++j)
          acc[i][j] = __builtin_amdgcn_mfma_f32_16x16x32_f16(abuf[cur][i], bbuf[cur][j], acc[i][j], 0, 0, 0);
      __builtin_amdgcn_s_setprio(0);
    }

    // epilogue: d' = e2 - 2*dot; per-lane (d1,i1,d2). cw index ascending -> '<' keeps first.
    const int cwb = nc * 128 + wc * 64;
    #pragma unroll
    for (int i = 0; i < 4; ++i) {
      const int cw0 = cwb + i * 16 + quad * 4;    // C/D: row = quad*4 + r (codeword)
      float ee[4];
      #pragma unroll
      for (int r = 0; r < 4; ++r) ee[r] = e2l[cw0 + r];
      #pragma unroll
      for (int j = 0; j < 4; ++j) {
        #pragma unroll
        for (int r = 0; r < 4; ++r) {
          const float d = fmaf(-2.0f, acc[i][j][r], ee[r]);
          const bool lt = d < d1[j];
          const float hi = lt ? d1[j] : d;
          d1[j] = lt ? d : d1[j];
          i1[j] = lt ? (cw0 + r) : i1[j];
          d2[j] = fminf(d2[j], hi);
        }
      }
    }
  }

  // cross-quad butterfly (lanes l, l^16, l^32 share pixel col = lane&15)
  #pragma unroll
  for (int j = 0; j < 4; ++j) {
    #pragma unroll
    for (int m = 16; m <= 32; m <<= 1) {
      const float od1 = __shfl_xor(d1[j], m, 64);
      const int   oi1 = __shfl_xor(i1[j], m, 64);
      const float od2 = __shfl_xor(d2[j], m, 64);
      const bool take = (od1 < d1[j]) || (od1 == d1[j] && oi1 < i1[j]);
      const float hi = take ? d1[j] : od1;
      d1[j] = take ? od1 : d1[j];
      i1[j] = take ? oi1 : i1[j];
      d2[j] = fminf(fminf(d2[j], od2), hi);
    }
  }

  // cross-wave (wc) merge via LDS (reuse Zl); zsq/dsum/fid slices for loss + out-write
  __syncthreads();
  float* rd1  = (float*)Zl;          // [0..256)
  int*   ri1  = (int*)Zl + 256;      // [256..512)
  float* rd2  = (float*)Zl + 512;    // [512..768)
  float* zsq  = (float*)Zl + 768;    // [768..1024)
  float* dsum = (float*)Zl + 1024;   // [1024..1152)
  int*   fid  = (int*)Zl + 1152;     // [1152..1280)
  if (lane < 16) {
    #pragma unroll
    for (int j = 0; j < 4; ++j) {
      const int p = wp * 64 + j * 16 + ln;
      rd1[wc * 128 + p] = d1[j];
      ri1[wc * 128 + p] = i1[j];
      rd2[wc * 128 + p] = d2[j];
    }
  }
  zsq[tid] = s_z2;
  __syncthreads();
  if (tid < 128) {
    const float a1 = rd1[tid], b1 = rd1[128 + tid];
    const int   ai = ri1[tid], bi = ri1[128 + tid];
    const float a2 = rd2[tid], b2 = rd2[128 + tid];
    const bool take = (b1 < a1) || (b1 == a1 && bi < ai);
    const float d1f = take ? b1 : a1;
    const int   i1f = take ? bi : ai;
    const float hi  = take ? a1 : b1;
    const float d2f = fminf(fminf(a2, b2), hi);
    fid[tid]  = i1f;
    dsum[tid] = d1f;
    if ((d2f - d1f) <= TAU) {   // fp16 gap error sigma ~3e-2; TAU = 5 sigma
      const int pos = atomicAdd(ccount, 1);
      clist[pos] = ptile + tid;
    }
  }
  __syncthreads();
  // block loss partial: Σ_{px} d1 + Σ z²  -> one atomic per block
  if (tid < 64) {
    float v = zsq[tid] + zsq[tid + 64] + zsq[tid + 128] + zsq[tid + 192]
            + dsum[tid] + dsum[tid + 64];
    #pragma unroll
    for (int off = 32; off; off >>= 1) v += __shfl_down(v, off, 64);
    if (tid == 0) atomicAdd(acc_out, v);
  }
  // fused output write: thread t -> pixel (t&127), channel half (t>>7)*128.
  // Wave lanes = 64 consecutive px at fixed channel -> coalesced 256B stores;
  // cb rows gathered from L2 (1 MB resident).
  {
    const int pl = tid & 127, cs = tid >> 7;
    const int id = fid[pl];
    const float* er = cb + (size_t)id * C_DIM + cs * 128;
    float* orow = out + (size_t)b * (C_DIM * HW) + (size_t)(cs * 128) * HW + pb + pl;
    #pragma unroll 8
    for (int c = 0; c < 128; c += 4) {
      const float4 ev = *(const float4*)(er + c);
      orow[(size_t)(c + 0) * HW] = ev.x;
      orow[(size_t)(c + 1) * HW] = ev.y;
      orow[(size_t)(c + 2) * HW] = ev.z;
      orow[(size_t)(c + 3) * HW] = ev.w;
    }
  }
}

// K2: exact fp32 rescan. One block per group of 4 contested pixels, all 1024
// codewords in-block. fma chain per (cw,px) bit-identical to prior passing
// version. After the argmin, each wave rewrites the out row for its pixel.
// Block 0 also writes the final loss at START (acc final by stream order).
__global__ __launch_bounds__(256)
void rescan_kernel(const float* __restrict__ z, const float* __restrict__ cb,
                   const float* __restrict__ e2, const int* __restrict__ clist,
                   const int* __restrict__ ccount, float* __restrict__ out,
                   const float* __restrict__ acc, float* __restrict__ loss_out) {
  if (blockIdx.x == 0 && threadIdx.x == 0)
    *loss_out = 1.25f * (*acc) * (1.0f / 16777216.0f);
  __shared__ __align__(16) float zl[4][C_DIM];    // [px][k] -> float4 broadcast reads
  __shared__ int pxs[4];
  __shared__ unsigned long long bestk[4];
  const int n = *ccount;
  const int ngroups = (n + 3) >> 2;
  for (int g = blockIdx.x; g < ngroups; g += gridDim.x) {
    const int base = g * 4;
    if ((int)threadIdx.x < 4) {
      pxs[threadIdx.x] = clist[min(base + (int)threadIdx.x, n - 1)];  // pad w/ dup (idempotent)
      bestk[threadIdx.x] = ~0ULL;
    }
    __syncthreads();
    {
      const int k = threadIdx.x;
      #pragma unroll
      for (int i = 0; i < 4; ++i) {
        const int gp = pxs[i];
        zl[i][k] = z[(size_t)(gp >> 12) * (C_DIM * HW) + (size_t)k * HW + (gp & 4095)];
      }
    }
    __syncthreads();
    unsigned long long mykey[4] = {~0ULL, ~0ULL, ~0ULL, ~0ULL};
    #pragma unroll 1
    for (int o = 0; o < 4; ++o) {
      const int cw = o * 256 + (int)threadIdx.x;
      const float* row = cb + (size_t)cw * C_DIM;
      float dot[4] = {0.f, 0.f, 0.f, 0.f};
      #pragma unroll 4
      for (int k0 = 0; k0 < C_DIM; k0 += 4) {
        const float4 ev = *(const float4*)(row + k0);   // coalesced-by-row, L2-hot
        #pragma unroll
        for (int i = 0; i < 4; ++i) {
          const float4 zz = *(const float4*)&zl[i][k0]; // uniform addr -> LDS broadcast
          dot[i] = fmaf(ev.x, zz.x, dot[i]);
          dot[i] = fmaf(ev.y, zz.y, dot[i]);
          dot[i] = fmaf(ev.z, zz.z, dot[i]);
          dot[i] = fmaf(ev.w, zz.w, dot[i]);
        }
      }
      const float ee = e2[cw];
      #pragma unroll
      for (int i = 0; i < 4; ++i) {
        const float d = fmaf(-2.0f, dot[i], ee);
        const unsigned long long key = ((unsigned long long)fenc(d) << 32) | (unsigned)cw;
        mykey[i] = key < mykey[i] ? key : mykey[i];
      }
    }
    // wave-level u64 min reduce, then 1 shared atomic per wave per pixel
    #pragma unroll
    for (int i = 0; i < 4; ++i) {
      unsigned long long k = mykey[i];
      #pragma unroll
      for (int off = 32; off; off >>= 1) {
        const unsigned long long ok = __shfl_xor(k, off, 64);
        k = ok < k ? ok : k;
      }
      if ((threadIdx.x & 63) == 0) atomicMin(&bestk[i], k);
    }
    __syncthreads();
    // rewrite out row for this wave's pixel (duplicate-padded px: identical writes)
    {
      const int i = (int)threadIdx.x >> 6;
      const int l = (int)threadIdx.x & 63;
      const int gp = pxs[i];
      const int id = (int)(unsigned)(bestk[i] & 0xFFFFFFFFull);
      const float* er = cb + (size_t)id * C_DIM;
      float* orow = out + (size_t)(gp >> 12) * (C_DIM * HW) + (gp & 4095);
      const float4 ev = *(const float4*)(er + l * 4);   // coalesced row read
      orow[(size_t)(l * 4 + 0) * HW] = ev.x;
      orow[(size_t)(l * 4 + 1) * HW] = ev.y;
      orow[(size_t)(l * 4 + 2) * HW] = ev.z;
      orow[(size_t)(l * 4 + 3) * HW] = ev.w;
    }
    __syncthreads();
  }
}

extern "C" void kernel_launch(void* const* d_in, const int* in_sizes, int n_in,
                              void* d_out, int out_size, void* d_ws, size_t ws_size,
                              hipStream_t stream) {
  const float* z  = (const float*)d_in[0];
  const float* cb = (const float*)d_in[1];
  float* out = (float*)d_out;
  char* ws = (char*)d_ws;

  float*    acc    = (float*)ws;
  int*      ccount = (int*)(ws + 8);
  float*    e2     = (float*)(ws + 4096);
  _Float16* EhfP   = (_Float16*)(ws + 8192);
  int*      clist  = (int*)(ws + 532480);

  prep_kernel<<<384, 256, 0, stream>>>(cb, EhfP, e2, acc, ccount);
  screen_kernel<<<NPIX / 128, 256, 0, stream>>>(z, EhfP, e2, cb, clist, ccount, acc, out);
  rescan_kernel<<<1024, 256, 0, stream>>>(z, cb, e2, clist, ccount, out, acc,
                                          out + 16777216);
}